// Round 2
// baseline (2545.655 us; speedup 1.0000x reference)
//
#include <hip/hip_runtime.h>
#include <hip/hip_bf16.h>
#include <cstdint>
#include <cstddef>

#define N_NODES 100000
#define N_EDGES 3200000
#define IN_DIM 512
#define HIDDEN 256
#define NUM_CLASSES 1000
#define SCAN_CHUNK 1024

// ---------------- bf16 helpers ----------------

__device__ __forceinline__ float bf2f(unsigned short u) {
  union { unsigned int i; float f; } c; c.i = ((unsigned int)u) << 16; return c.f;
}
__device__ __forceinline__ unsigned short f2bf(float f) {
  union { float f; unsigned int i; } c; c.f = f;
  unsigned int i = c.i;
  unsigned int r = i + 0x7FFFu + ((i >> 16) & 1u);  // round-to-nearest-even
  return (unsigned short)(r >> 16);
}

// ---------------- CSR build ----------------

__global__ void k_zero_cnt(int* __restrict__ cnt, int n) {
  int i = blockIdx.x * blockDim.x + threadIdx.x;
  if (i < n) cnt[i] = 0;
}

__global__ void k_hist(const int* __restrict__ col, int* __restrict__ cnt, int e) {
  int i = blockIdx.x * blockDim.x + threadIdx.x;
  if (i < e) atomicAdd(&cnt[col[i]], 1);
}

__global__ void k_scan_block_sums(const int* __restrict__ cnt, int* __restrict__ blk, int n) {
  __shared__ int s[256];
  int t = threadIdx.x;
  int base = blockIdx.x * SCAN_CHUNK + t * 4;
  int sum = 0;
#pragma unroll
  for (int k = 0; k < 4; ++k) { int i = base + k; if (i < n) sum += cnt[i]; }
  s[t] = sum; __syncthreads();
  for (int off = 128; off > 0; off >>= 1) {
    if (t < off) s[t] += s[t + off];
    __syncthreads();
  }
  if (t == 0) blk[blockIdx.x] = s[0];
}

// 128 threads; nb <= 128. Exclusive-scans blk in place, writes grand total.
__global__ void k_scan_tops(int* __restrict__ blk, int nb, int* __restrict__ total) {
  __shared__ int s[128];
  int t = threadIdx.x;
  int v = (t < nb) ? blk[t] : 0;
  s[t] = v; __syncthreads();
  for (int off = 1; off < 128; off <<= 1) {
    int x = (t >= off) ? s[t - off] : 0;
    __syncthreads();
    s[t] += x;
    __syncthreads();
  }
  if (t < nb) blk[t] = s[t] - v;     // exclusive block offsets
  if (t == 0) *total = s[127];       // == E (csr_off[N])
}

__global__ void k_scan_final(const int* __restrict__ cnt, const int* __restrict__ blk,
                             int* __restrict__ csr_off, int* __restrict__ cursor,
                             float* __restrict__ dinv, int n) {
  __shared__ int s[256];
  int t = threadIdx.x;
  int base = blockIdx.x * SCAN_CHUNK + t * 4;
  int v[4]; int sum = 0;
#pragma unroll
  for (int k = 0; k < 4; ++k) { int i = base + k; v[k] = (i < n) ? cnt[i] : 0; sum += v[k]; }
  s[t] = sum; __syncthreads();
  for (int off = 1; off < 256; off <<= 1) {
    int x = (t >= off) ? s[t - off] : 0;
    __syncthreads();
    s[t] += x;
    __syncthreads();
  }
  int run = blk[blockIdx.x] + ((t == 0) ? 0 : s[t - 1]);
#pragma unroll
  for (int k = 0; k < 4; ++k) {
    int i = base + k;
    if (i < n) {
      csr_off[i] = run;
      cursor[i] = run;
      dinv[i] = rsqrtf((float)(v[k] + 1));  // deg = incoming edges + self loop
    }
    run += v[k];
  }
}

__global__ void k_fill(const int* __restrict__ row, const int* __restrict__ col,
                       int* __restrict__ cursor, int* __restrict__ csr_row, int e) {
  int i = blockIdx.x * blockDim.x + threadIdx.x;
  if (i < e) {
    int c = col[i];
    int slot = atomicAdd(&cursor[c], 1);
    csr_row[slot] = row[i];
  }
}

// ---------------- SGEMM (fp32 compute, 64x64 tile, 4x4 per thread) ----------------
// C[m,n] = (A[m,:] @ B[:,n]) * (ROW_SCALE ? rowscale[m] : 1) + (ADD_BIAS ? bias[n] : 0)
// A may be fp32 or bf16 (row-major [M,K]); B is fp32 [K,N]; C fp32 or bf16.

template <bool A_BF16, bool C_BF16, bool ROW_SCALE, bool ADD_BIAS>
__global__ __launch_bounds__(256) void k_sgemm(
    const void* __restrict__ Av, const float* __restrict__ B,
    const float* __restrict__ rowscale, const float* __restrict__ bias,
    void* __restrict__ Cv, int M, int N, int K) {
  __shared__ float As[16][68];   // [k][m], pad 68 -> <=2-way write conflicts (free)
  __shared__ float Bs[16][64];   // [k][n]
  int tid = threadIdx.x;
  int tx = tid & 15, ty = tid >> 4;
  int m0 = blockIdx.y * 64, n0 = blockIdx.x * 64;
  int a_m = tid >> 2, a_k = (tid & 3) * 4;    // A: 4 elems along k per thread
  int b_k = tid >> 4, b_n = (tid & 15) * 4;   // B: float4 along n
  float acc[4][4] = {};
  for (int k0 = 0; k0 < K; k0 += 16) {
    float4 av = make_float4(0.f, 0.f, 0.f, 0.f);
    int gm = m0 + a_m;
    if (gm < M) {
      if constexpr (A_BF16) {
        ushort4 t = *(const ushort4*)((const unsigned short*)Av + (size_t)gm * K + k0 + a_k);
        av = make_float4(bf2f(t.x), bf2f(t.y), bf2f(t.z), bf2f(t.w));
      } else {
        av = *(const float4*)((const float*)Av + (size_t)gm * K + k0 + a_k);
      }
    }
    As[a_k + 0][a_m] = av.x;
    As[a_k + 1][a_m] = av.y;
    As[a_k + 2][a_m] = av.z;
    As[a_k + 3][a_m] = av.w;

    float4 bv = make_float4(0.f, 0.f, 0.f, 0.f);
    int gn = n0 + b_n;
    const float* brow = B + (size_t)(k0 + b_k) * N;
    if (gn + 3 < N) {
      bv = *(const float4*)(brow + gn);
    } else {
      float t4[4] = {0.f, 0.f, 0.f, 0.f};
      for (int j = 0; j < 4; ++j) if (gn + j < N) t4[j] = brow[gn + j];
      bv = make_float4(t4[0], t4[1], t4[2], t4[3]);
    }
    *(float4*)(&Bs[b_k][b_n]) = bv;
    __syncthreads();
#pragma unroll
    for (int kk = 0; kk < 16; ++kk) {
      float4 a = *(const float4*)(&As[kk][ty * 4]);
      float4 b = *(const float4*)(&Bs[kk][tx * 4]);
      float aa[4] = {a.x, a.y, a.z, a.w};
      float bb[4] = {b.x, b.y, b.z, b.w};
#pragma unroll
      for (int i = 0; i < 4; ++i)
#pragma unroll
        for (int j = 0; j < 4; ++j)
          acc[i][j] = fmaf(aa[i], bb[j], acc[i][j]);
    }
    __syncthreads();
  }
#pragma unroll
  for (int i = 0; i < 4; ++i) {
    int gm = m0 + ty * 4 + i;
    if (gm >= M) continue;
    float rs = ROW_SCALE ? rowscale[gm] : 1.f;
    int gn = n0 + tx * 4;
    float o[4];
#pragma unroll
    for (int j = 0; j < 4; ++j) o[j] = acc[i][j] * rs;
    if (ADD_BIAS) {
      for (int j = 0; j < 4; ++j) if (gn + j < N) o[j] += bias[gn + j];
    }
    if constexpr (C_BF16) {
      unsigned short* crow = (unsigned short*)Cv + (size_t)gm * N;
      if (gn + 3 < N) {
        ushort4 p; p.x = f2bf(o[0]); p.y = f2bf(o[1]); p.z = f2bf(o[2]); p.w = f2bf(o[3]);
        *(ushort4*)(crow + gn) = p;
      } else {
        for (int j = 0; j < 4; ++j) if (gn + j < N) crow[gn + j] = f2bf(o[j]);
      }
    } else {
      float* crow = (float*)Cv + (size_t)gm * N;
      if (gn + 3 < N) {
        *(float4*)(crow + gn) = make_float4(o[0], o[1], o[2], o[3]);
      } else {
        for (int j = 0; j < 4; ++j) if (gn + j < N) crow[gn + j] = o[j];
      }
    }
  }
}

// ---------------- Aggregation: one wave per node, 4 bf16 channels per lane ----------------
// out[c] = bf16( relu(dinv[c] * (sum_{e: col=c} Hs[row_e] + Hs[c]) + bias) )
// Hs already carries the dinv[row] factor (fused into GEMM epilogue). fp32 accumulate.

__global__ __launch_bounds__(256) void k_agg_bias_relu(
    const ushort4* __restrict__ Hs, const int* __restrict__ csr_off,
    const int* __restrict__ csr_row, const float* __restrict__ dinv,
    const float* __restrict__ bias, ushort4* __restrict__ out, int n) {
  int node = blockIdx.x * 4 + (threadIdx.x >> 6);
  if (node >= n) return;
  int lane = threadIdx.x & 63;                 // HIDDEN/4 = 64 lanes x 4 channels
  ushort4 sv = Hs[(size_t)node * 64 + lane];   // self loop
  float ax = bf2f(sv.x), ay = bf2f(sv.y), az = bf2f(sv.z), aw = bf2f(sv.w);
  int beg = csr_off[node], end = csr_off[node + 1];
  for (int j = beg; j < end; ++j) {
    int r = csr_row[j];
    ushort4 v = Hs[(size_t)r * 64 + lane];
    ax += bf2f(v.x); ay += bf2f(v.y); az += bf2f(v.z); aw += bf2f(v.w);
  }
  float di = dinv[node];
  float4 b = ((const float4*)bias)[lane];
  ushort4 o;
  o.x = f2bf(fmaxf(fmaf(ax, di, b.x), 0.f));
  o.y = f2bf(fmaxf(fmaf(ay, di, b.y), 0.f));
  o.z = f2bf(fmaxf(fmaf(az, di, b.z), 0.f));
  o.w = f2bf(fmaxf(fmaf(aw, di, b.w), 0.f));
  out[(size_t)node * 64 + lane] = o;
}

// ---------------- launch ----------------

extern "C" void kernel_launch(void* const* d_in, const int* in_sizes, int n_in,
                              void* d_out, int out_size, void* d_ws, size_t ws_size,
                              hipStream_t stream) {
  const float* x   = (const float*)d_in[0];
  const int*   ei  = (const int*)d_in[1];   // int32! (JAX x64 disabled; harness: integer -> int*)
  const float* W1  = (const float*)d_in[2];
  const float* b1  = (const float*)d_in[3];
  const float* W2  = (const float*)d_in[4];
  const float* b2  = (const float*)d_in[5];
  const float* Wfc = (const float*)d_in[6];
  const float* bfc = (const float*)d_in[7];
  float* out = (float*)d_out;

  const int* row = ei;             // sources
  const int* col = ei + N_EDGES;   // targets

  // Scratch carved from d_out (400 MB fp32; regions dead before FC writes):
  //   bufA (pre-agg features Hs, bf16, 51.2 MB) + csr_row (12.8 MB)
  char* q = (char*)d_out;
  unsigned short* bufA = (unsigned short*)q;                       // [N_NODES*HIDDEN] bf16
  int* csr_row = (int*)(q + (size_t)N_NODES * HIDDEN * 2);         // offset 51.2e6 (256-aligned)

  // d_ws: small CSR arrays + post-agg feature buffer (must survive into FC)
  char* p = (char*)d_ws;
  auto alloc = [&](size_t bytes) { char* r = p; p += (bytes + 255) & ~(size_t)255; return r; };
  int*   cnt     = (int*)alloc(sizeof(int) * N_NODES);
  int*   csr_off = (int*)alloc(sizeof(int) * (N_NODES + 1));
  int*   cursor  = (int*)alloc(sizeof(int) * N_NODES);
  int*   blk     = (int*)alloc(sizeof(int) * 128);
  float* dinv    = (float*)alloc(sizeof(float) * N_NODES);
  unsigned short* bufB = (unsigned short*)alloc(sizeof(unsigned short) * (size_t)N_NODES * HIDDEN);

  const int nscan = (N_NODES + SCAN_CHUNK - 1) / SCAN_CHUNK;  // 98 (<=128)

  hipLaunchKernelGGL(k_zero_cnt, dim3((N_NODES + 255) / 256), dim3(256), 0, stream, cnt, N_NODES);
  hipLaunchKernelGGL(k_hist, dim3((N_EDGES + 255) / 256), dim3(256), 0, stream, col, cnt, N_EDGES);
  hipLaunchKernelGGL(k_scan_block_sums, dim3(nscan), dim3(256), 0, stream, cnt, blk, N_NODES);
  hipLaunchKernelGGL(k_scan_tops, dim3(1), dim3(128), 0, stream, blk, nscan, csr_off + N_NODES);
  hipLaunchKernelGGL(k_scan_final, dim3(nscan), dim3(256), 0, stream, cnt, blk, csr_off, cursor, dinv, N_NODES);
  hipLaunchKernelGGL(k_fill, dim3((N_EDGES + 255) / 256), dim3(256), 0, stream, row, col, cursor, csr_row, N_EDGES);

  // Layer 1: Hs = bf16((x @ W1) * dinv[row]) -> agg -> relu -> bufB (bf16)
  hipLaunchKernelGGL((k_sgemm<false, true, true, false>),
                     dim3(HIDDEN / 64, (N_NODES + 63) / 64), dim3(256), 0, stream,
                     x, W1, dinv, (const float*)nullptr, bufA, N_NODES, HIDDEN, IN_DIM);
  hipLaunchKernelGGL(k_agg_bias_relu, dim3((N_NODES + 3) / 4), dim3(256), 0, stream,
                     (const ushort4*)bufA, csr_off, csr_row, dinv, b1, (ushort4*)bufB, N_NODES);

  // Layer 2 (A is bf16 now)
  hipLaunchKernelGGL((k_sgemm<true, true, true, false>),
                     dim3(HIDDEN / 64, (N_NODES + 63) / 64), dim3(256), 0, stream,
                     bufB, W2, dinv, (const float*)nullptr, bufA, N_NODES, HIDDEN, HIDDEN);
  hipLaunchKernelGGL(k_agg_bias_relu, dim3((N_NODES + 3) / 4), dim3(256), 0, stream,
                     (const ushort4*)bufA, csr_off, csr_row, dinv, b2, (ushort4*)bufB, N_NODES);

  // FC: out = bufB @ Wfc + bfc   (overwrites the d_out scratch region; bufB lives in d_ws)
  hipLaunchKernelGGL((k_sgemm<true, false, false, true>),
                     dim3((NUM_CLASSES + 63) / 64, (N_NODES + 63) / 64), dim3(256), 0, stream,
                     bufB, Wfc, (const float*)nullptr, bfc, out, N_NODES, NUM_CLASSES, HIDDEN);
}